// Round 3
// baseline (322.235 us; speedup 1.0000x reference)
//
#include <hip/hip_runtime.h>
#include <stdint.h>
#include <stddef.h>

// ---------- types ----------
typedef __attribute__((ext_vector_type(8))) short s16x8;
typedef __attribute__((ext_vector_type(4))) short s16x4;
typedef __attribute__((ext_vector_type(4))) float f32x4;

#define S_LEN 2048
#define HID 2048
#define QKV_N 3072
#define NHEAD 32
#define NKVH 8

__device__ __forceinline__ unsigned short f2bf(float f) {
  union { float f; unsigned u; } a; a.f = f;
  unsigned u = a.u;
  u += 0x7fffu + ((u >> 16) & 1u);
  return (unsigned short)(u >> 16);
}
__device__ __forceinline__ float bf2f(unsigned short h) {
  union { unsigned u; float f; } a; a.u = ((unsigned)h) << 16;
  return a.f;
}
__device__ __forceinline__ void gl_lds16(const unsigned short* g, short* l) {
  __builtin_amdgcn_global_load_lds(
      (const __attribute__((address_space(1))) unsigned int*)g,
      (__attribute__((address_space(3))) unsigned int*)l, 16, 0, 0);
}

// ---------- 1) fp32 -> bf16 convert ----------
__global__ void k_convert(const float* __restrict__ x, const float* __restrict__ wq,
                          const float* __restrict__ wk, const float* __restrict__ wv,
                          const float* __restrict__ wo, unsigned short* __restrict__ dst) {
  const unsigned n4 = 18874368u / 4u;
  for (unsigned i = blockIdx.x * blockDim.x + threadIdx.x; i < n4;
       i += gridDim.x * blockDim.x) {
    unsigned e = i * 4u;
    const float* src; unsigned off;
    if (e < 8388608u)       { src = x;  off = e; }
    else if (e < 12582912u) { src = wq; off = e - 8388608u; }
    else if (e < 13631488u) { src = wk; off = e - 12582912u; }
    else if (e < 14680064u) { src = wv; off = e - 13631488u; }
    else                    { src = wo; off = e - 14680064u; }
    f32x4 v = *(const f32x4*)(src + off);
    s16x4 o;
    o[0] = (short)f2bf(v[0]); o[1] = (short)f2bf(v[1]);
    o[2] = (short)f2bf(v[2]); o[3] = (short)f2bf(v[3]);
    *(s16x4*)(dst + e) = o;
  }
}

// ---------- 2) RoPE cos/sin table [2048][32] ----------
__global__ void k_rope_table(float* __restrict__ cost, float* __restrict__ sint) {
  int idx = blockIdx.x * 256 + threadIdx.x;
  int i = idx & 31, s = idx >> 5;
  float inv = powf(10000.0f, -(float)(2 * i) / 64.0f);
  float ang = (float)s * inv;
  cost[idx] = cosf(ang);
  sint[idx] = sinf(ang);
}

// ---------- 3/7) GEMM ----------
template <int MODE>
__global__ __launch_bounds__(256) void k_gemm(
    const unsigned short* __restrict__ A,
    const unsigned short* __restrict__ W0, const unsigned short* __restrict__ W1,
    const unsigned short* __restrict__ W2,
    const float* __restrict__ b0, const float* __restrict__ b1, const float* __restrict__ b2,
    unsigned short* __restrict__ Cb, float* __restrict__ Cf) {
  __shared__ short lA[128 * 32];
  __shared__ short lB[128 * 32];
  const int K = 2048;
  int tid = threadIdx.x;
  int wave = tid >> 6, lane = tid & 63;
  int l15 = lane & 15, lg = lane >> 4;
  int tn = blockIdx.x, tm = blockIdx.y;
  const unsigned short* W; const float* bias = nullptr; int col0;
  if constexpr (MODE == 0) {
    if (tn < 16)      { W = W0; bias = b0; col0 = tn * 128; }
    else if (tn < 20) { W = W1; bias = b1; col0 = (tn - 16) * 128; }
    else              { W = W2; bias = b2; col0 = (tn - 20) * 128; }
  } else { W = W0; col0 = tn * 128; }
  int m0 = tm * 128;
  int wm = wave >> 1, wn = wave & 1;

  const unsigned short* gA0 = A + (size_t)(m0 + (tid >> 2)) * K + (tid & 3) * 8;
  const unsigned short* gA1 = gA0 + (size_t)64 * K;
  const unsigned short* gB0 = W + (size_t)(col0 + (tid >> 2)) * K + (tid & 3) * 8;
  const unsigned short* gB1 = gB0 + (size_t)64 * K;
  short* sA0 = &lA[wave * 512];
  short* sA1 = &lA[2048 + wave * 512];
  short* sB0 = &lB[wave * 512];
  short* sB1 = &lB[2048 + wave * 512];

  f32x4 acc[4][4];
#pragma unroll
  for (int m = 0; m < 4; ++m)
#pragma unroll
    for (int n = 0; n < 4; ++n) acc[m][n] = (f32x4){0.f, 0.f, 0.f, 0.f};

  for (int kt = 0; kt < K; kt += 32) {
    __syncthreads();
    gl_lds16(gA0 + kt, sA0);
    gl_lds16(gA1 + kt, sA1);
    gl_lds16(gB0 + kt, sB0);
    gl_lds16(gB1 + kt, sB1);
    asm volatile("s_waitcnt vmcnt(0)" ::: "memory");
    __syncthreads();
    s16x8 af[4], bfr[4];
    const short* pa = &lA[(wm * 64 + l15) * 32 + lg * 8];
    const short* pb = &lB[(wn * 64 + l15) * 32 + lg * 8];
#pragma unroll
    for (int m = 0; m < 4; ++m) af[m] = *(const s16x8*)(pa + m * 512);
#pragma unroll
    for (int n = 0; n < 4; ++n) bfr[n] = *(const s16x8*)(pb + n * 512);
#pragma unroll
    for (int m = 0; m < 4; ++m)
#pragma unroll
      for (int n = 0; n < 4; ++n)
        acc[m][n] = __builtin_amdgcn_mfma_f32_16x16x32_bf16(af[m], bfr[n], acc[m][n], 0, 0, 0);
  }

#pragma unroll
  for (int n = 0; n < 4; ++n) {
    int lcol = col0 + wn * 64 + n * 16 + l15;
    int gcol = tn * 128 + wn * 64 + n * 16 + l15;
    float bv = 0.f;
    if constexpr (MODE == 0) bv = bias[lcol];
#pragma unroll
    for (int m = 0; m < 4; ++m) {
      int row = m0 + wm * 64 + m * 16 + lg * 4;
#pragma unroll
      for (int r = 0; r < 4; ++r) {
        float v = acc[m][n][r] + bv;
        if constexpr (MODE == 0)
          Cb[(size_t)(row + r) * QKV_N + gcol] = f2bf(v);
        else
          Cf[(size_t)(row + r) * HID + gcol] = v;
      }
    }
  }
}

// ---------- 4) RoPE in-place ----------
__global__ void k_rope_apply(unsigned short* __restrict__ qkv,
                             const float* __restrict__ cost, const float* __restrict__ sint) {
  int t = blockIdx.x * blockDim.x + threadIdx.x;
  int chunk = t & 3;
  int head = (t >> 2) % 40;
  int row = t / 160;
  int colb = head < 32 ? head * 64 : 2048 + (head - 32) * 64;
  int d0 = chunk * 8;
  int s = row & (S_LEN - 1);
  unsigned short* p = qkv + (size_t)row * QKV_N + colb;
  s16x8 lo = *(s16x8*)(p + d0);
  s16x8 hi = *(s16x8*)(p + 32 + d0);
  const float* cb = cost + s * 32 + d0;
  const float* sb = sint + s * 32 + d0;
  f32x4 c0 = *(const f32x4*)cb, c1 = *(const f32x4*)(cb + 4);
  f32x4 s0 = *(const f32x4*)sb, s1 = *(const f32x4*)(sb + 4);
  float cc[8] = {c0[0], c0[1], c0[2], c0[3], c1[0], c1[1], c1[2], c1[3]};
  float ss[8] = {s0[0], s0[1], s0[2], s0[3], s1[0], s1[1], s1[2], s1[3]};
  s16x8 nlo, nhi;
#pragma unroll
  for (int j = 0; j < 8; ++j) {
    float xl = bf2f((unsigned short)lo[j]);
    float xh = bf2f((unsigned short)hi[j]);
    nlo[j] = (short)f2bf(xl * cc[j] - xh * ss[j]);
    nhi[j] = (short)f2bf(xh * cc[j] + xl * ss[j]);
  }
  *(s16x8*)(p + d0) = nlo;
  *(s16x8*)(p + 32 + d0) = nhi;
}

// ---------- 5) V transpose ----------
__global__ void k_vtrans(const unsigned short* __restrict__ qkv, unsigned short* __restrict__ vt) {
  __shared__ unsigned short t[64][80];
  int ts = blockIdx.x & 63, td = blockIdx.x >> 6;
  int tid = threadIdx.x;
#pragma unroll
  for (int L = 0; L < 2; ++L) {
    int c = L * 256 + tid;
    int row = c >> 3, ch = c & 7;
    const unsigned short* src = qkv + (size_t)(ts * 64 + row) * QKV_N + 2560 + td * 64 + ch * 8;
    s16x8 v = *(const s16x8*)src;
    int cs = (ch * 8) ^ ((row >> 3) << 3);
    *(s16x8*)&t[row][cs] = v;
  }
  __syncthreads();
  int b = (ts * 64) >> 11;
  int s0 = (ts * 64) & (S_LEN - 1);
#pragma unroll
  for (int L = 0; L < 2; ++L) {
    int c = L * 256 + tid;
    int d = c >> 3, sc = c & 7;
    s16x8 o;
#pragma unroll
    for (int j = 0; j < 8; ++j) o[j] = (short)t[sc * 8 + j][d ^ (sc << 3)];
    unsigned short* dst = vt + ((size_t)((b * 8 + td) * 64 + d)) * 2048 + s0 + sc * 8;
    *(s16x8*)dst = o;
  }
}

// ---------- 6) GQA causal flash attention, swapped-QK^T, longest-first ----------
// block = 4 heads of one KV group at one q-tile; grid 1024, tile = 63 - (bi>>4).
// Swapped: S^T = mfma(K,Q) -> lane l15 = q, in-lane 16 k-values -> row-reduce
// is in-lane + 2 shfl. P transposed to A-layout through wave-private LDS.
#define PSTR 72
__global__ __launch_bounds__(256, 4) void k_attn(const unsigned short* __restrict__ qkv,
                                                 const unsigned short* __restrict__ vt,
                                                 unsigned short* __restrict__ aout) {
  __shared__ unsigned short pl[4][32 * PSTR];
  int wave = threadIdx.x >> 6, lane = threadIdx.x & 63;
  int l15 = lane & 15, lg = lane >> 4;
  int bi = blockIdx.x;              // 0..1023
  int t = 63 - (bi >> 4);           // longest-first
  int hg = bi & 7;
  int b = (bi >> 3) & 1;
  int h = hg * 4 + wave;
  int q0 = t * 32;
  int kbmax = t >> 1;

  const unsigned short* qb_ = qkv + (size_t)(b * S_LEN) * QKV_N + h * 64;
  const unsigned short* kb_ = qkv + (size_t)(b * S_LEN) * QKV_N + 2048 + hg * 64;
  const unsigned short* vb_ = vt + (size_t)((b * NKVH + hg) * 64) * 2048;
  unsigned short* pw = &pl[wave][0];

  // Q fragments (same layout serves as MFMA B-operand)
  s16x8 aq[2][2];
#pragma unroll
  for (int m = 0; m < 2; ++m)
#pragma unroll
    for (int ks = 0; ks < 2; ++ks)
      aq[m][ks] = *(const s16x8*)(qb_ + (size_t)(q0 + m * 16 + l15) * QKV_N + ks * 32 + lg * 8);

  f32x4 acc[2][4];
  float mrow[2], lrow[2];
#pragma unroll
  for (int m = 0; m < 2; ++m) {
#pragma unroll
    for (int dt = 0; dt < 4; ++dt) acc[m][dt] = (f32x4){0.f, 0.f, 0.f, 0.f};
    mrow[m] = -3.0e38f; lrow[m] = 0.f;
  }

  for (int kb = 0; kb <= kbmax; ++kb) {
    s16x8 bk[4][2];
#pragma unroll
    for (int nt = 0; nt < 4; ++nt)
#pragma unroll
      for (int ks = 0; ks < 2; ++ks)
        bk[nt][ks] = *(const s16x8*)(kb_ + (size_t)(kb * 64 + nt * 16 + l15) * QKV_N + ks * 32 + lg * 8);
    bool need_mask = (kb == kbmax);

#pragma unroll
    for (int m = 0; m < 2; ++m) {
      // S^T tile: rows k (lg*4+r within nt), col q = l15
      f32x4 z[4];
      __builtin_amdgcn_s_setprio(1);
#pragma unroll
      for (int nt = 0; nt < 4; ++nt) {
        f32x4 zz = (f32x4){0.f, 0.f, 0.f, 0.f};
        zz = __builtin_amdgcn_mfma_f32_16x16x32_bf16(bk[nt][0], aq[m][0], zz, 0, 0, 0);
        zz = __builtin_amdgcn_mfma_f32_16x16x32_bf16(bk[nt][1], aq[m][1], zz, 0, 0, 0);
        z[nt] = zz;
      }
      __builtin_amdgcn_s_setprio(0);
      float s[16];
      int q = q0 + m * 16 + l15;
#pragma unroll
      for (int nt = 0; nt < 4; ++nt)
#pragma unroll
        for (int r = 0; r < 4; ++r) {
          float v = z[nt][r] * 0.125f;
          if (need_mask) {
            int k = kb * 64 + nt * 16 + lg * 4 + r;
            if (k > q) v = -3.0e38f;
          }
          s[nt * 4 + r] = v;
        }
      float mx = s[0];
#pragma unroll
      for (int i = 1; i < 16; ++i) mx = fmaxf(mx, s[i]);
      mx = fmaxf(mx, __shfl_xor(mx, 16));
      mx = fmaxf(mx, __shfl_xor(mx, 32));
      float nm = fmaxf(mrow[m], mx);
      float corr = __expf(mrow[m] - nm);
      mrow[m] = nm;
      float rs = 0.f;
#pragma unroll
      for (int nt = 0; nt < 4; ++nt) {
        s16x4 pk;
#pragma unroll
        for (int r = 0; r < 4; ++r) {
          float p = __expf(s[nt * 4 + r] - nm);
          rs += p;
          pk[r] = (short)f2bf(p);
        }
        *(s16x4*)(pw + (m * 16 + l15) * PSTR + nt * 16 + lg * 4) = pk;
      }
      rs += __shfl_xor(rs, 16);
      rs += __shfl_xor(rs, 32);
      lrow[m] = lrow[m] * corr + rs;
      // rescale acc (rows q' = lg*4+r): redistribute corr from lane l15=q'
#pragma unroll
      for (int r = 0; r < 4; ++r) {
        float cr = __shfl(corr, lg * 4 + r);
#pragma unroll
        for (int dt = 0; dt < 4; ++dt) acc[m][dt][r] *= cr;
      }
    }

    // V fragments + PV
    s16x8 bv[4][2];
#pragma unroll
    for (int dt = 0; dt < 4; ++dt)
#pragma unroll
      for (int ks = 0; ks < 2; ++ks)
        bv[dt][ks] = *(const s16x8*)(vb_ + (size_t)(dt * 16 + l15) * 2048 + kb * 64 + ks * 32 + lg * 8);
    s16x8 pa[2][2];
#pragma unroll
    for (int m = 0; m < 2; ++m)
#pragma unroll
      for (int ks = 0; ks < 2; ++ks)
        pa[m][ks] = *(const s16x8*)(pw + (m * 16 + l15) * PSTR + ks * 32 + lg * 8);
    __builtin_amdgcn_s_setprio(1);
#pragma unroll
    for (int m = 0; m < 2; ++m)
#pragma unroll
      for (int dt = 0; dt < 4; ++dt) {
        acc[m][dt] = __builtin_amdgcn_mfma_f32_16x16x32_bf16(pa[m][0], bv[dt][0], acc[m][dt], 0, 0, 0);
        acc[m][dt] = __builtin_amdgcn_mfma_f32_16x16x32_bf16(pa[m][1], bv[dt][1], acc[m][dt], 0, 0, 0);
      }
    __builtin_amdgcn_s_setprio(0);
  }

  // epilogue: O = acc / l  (acc rows q = lg*4+r; lrow lives at l15=q -> shfl)
  unsigned short* ob = aout + (size_t)(b * S_LEN) * HID + h * 64;
#pragma unroll
  for (int m = 0; m < 2; ++m)
#pragma unroll
    for (int r = 0; r < 4; ++r) {
      float lr = __shfl(lrow[m], lg * 4 + r);
      float inv = 1.0f / lr;
#pragma unroll
      for (int dt = 0; dt < 4; ++dt)
        ob[(size_t)(q0 + m * 16 + lg * 4 + r) * HID + dt * 16 + l15] = f2bf(acc[m][dt][r] * inv);
    }
}

// ---------- launch ----------
extern "C" void kernel_launch(void* const* d_in, const int* in_sizes, int n_in,
                              void* d_out, int out_size, void* d_ws, size_t ws_size,
                              hipStream_t stream) {
  const float* x  = (const float*)d_in[0];
  const float* qw = (const float*)d_in[1];
  const float* qb = (const float*)d_in[2];
  const float* kw = (const float*)d_in[3];
  const float* kbias = (const float*)d_in[4];
  const float* vw = (const float*)d_in[5];
  const float* vbias = (const float*)d_in[6];
  const float* ow = (const float*)d_in[7];

  unsigned short* Xb  = (unsigned short*)d_ws;          // 8388608
  unsigned short* Wqb = Xb + 8388608;                   // 4194304
  unsigned short* Wkb = Wqb + 4194304;                  // 1048576
  unsigned short* Wvb = Wkb + 1048576;                  // 1048576
  unsigned short* Wob = Wvb + 1048576;                  // 4194304
  unsigned short* QKV = Wob + 4194304;                  // 4096*3072
  unsigned short* VT  = QKV + 12582912;                 // 2*8*64*2048
  unsigned short* AO  = VT + 2097152;                   // 4096*2048
  float* COS = (float*)(AO + 8388608);                  // 65536 f32
  float* SIN = COS + 65536;

  k_convert<<<1024, 256, 0, stream>>>(x, qw, kw, vw, ow, Xb);
  k_rope_table<<<256, 256, 0, stream>>>(COS, SIN);
  k_gemm<0><<<dim3(24, 32), 256, 0, stream>>>(Xb, Wqb, Wkb, Wvb, qb, kbias, vbias, QKV, nullptr);
  k_rope_apply<<<2560, 256, 0, stream>>>(QKV, COS, SIN);
  k_vtrans<<<512, 256, 0, stream>>>(QKV, VT);
  k_attn<<<1024, 256, 0, stream>>>(QKV, VT, AO);
  k_gemm<1><<<dim3(16, 32), 256, 0, stream>>>(AO, Wob, nullptr, nullptr,
                                              nullptr, nullptr, nullptr, nullptr, (float*)d_out);
}

// Round 4
// 227.496 us; speedup vs baseline: 1.4164x; 1.4164x over previous
//
#include <hip/hip_runtime.h>
#include <stdint.h>
#include <stddef.h>

// ---------- types ----------
typedef __attribute__((ext_vector_type(8))) short s16x8;
typedef __attribute__((ext_vector_type(4))) short s16x4;
typedef __attribute__((ext_vector_type(4))) float f32x4;

#define S_LEN 2048
#define HID 2048
#define QKV_N 3072
#define NHEAD 32
#define NKVH 8

__device__ __forceinline__ unsigned short f2bf(float f) {
  union { float f; unsigned u; } a; a.f = f;
  unsigned u = a.u;
  u += 0x7fffu + ((u >> 16) & 1u);
  return (unsigned short)(u >> 16);
}
__device__ __forceinline__ float bf2f(unsigned short h) {
  union { unsigned u; float f; } a; a.u = ((unsigned)h) << 16;
  return a.f;
}
__device__ __forceinline__ void gl_lds16(const unsigned short* g, short* l) {
  __builtin_amdgcn_global_load_lds(
      (const __attribute__((address_space(1))) unsigned int*)g,
      (__attribute__((address_space(3))) unsigned int*)l, 16, 0, 0);
}

// ---------- 1) fp32 -> bf16 convert ----------
__global__ void k_convert(const float* __restrict__ x, const float* __restrict__ wq,
                          const float* __restrict__ wk, const float* __restrict__ wv,
                          const float* __restrict__ wo, unsigned short* __restrict__ dst) {
  const unsigned n4 = 18874368u / 4u;
  for (unsigned i = blockIdx.x * blockDim.x + threadIdx.x; i < n4;
       i += gridDim.x * blockDim.x) {
    unsigned e = i * 4u;
    const float* src; unsigned off;
    if (e < 8388608u)       { src = x;  off = e; }
    else if (e < 12582912u) { src = wq; off = e - 8388608u; }
    else if (e < 13631488u) { src = wk; off = e - 12582912u; }
    else if (e < 14680064u) { src = wv; off = e - 13631488u; }
    else                    { src = wo; off = e - 14680064u; }
    f32x4 v = *(const f32x4*)(src + off);
    s16x4 o;
    o[0] = (short)f2bf(v[0]); o[1] = (short)f2bf(v[1]);
    o[2] = (short)f2bf(v[2]); o[3] = (short)f2bf(v[3]);
    *(s16x4*)(dst + e) = o;
  }
}

// ---------- 2) RoPE cos/sin table [2048][32] ----------
__global__ void k_rope_table(float* __restrict__ cost, float* __restrict__ sint) {
  int idx = blockIdx.x * 256 + threadIdx.x;
  int i = idx & 31, s = idx >> 5;
  float inv = powf(10000.0f, -(float)(2 * i) / 64.0f);
  float ang = (float)s * inv;
  cost[idx] = cosf(ang);
  sint[idx] = sinf(ang);
}

// ---------- 3/7) GEMM ----------
template <int MODE>
__global__ __launch_bounds__(256) void k_gemm(
    const unsigned short* __restrict__ A,
    const unsigned short* __restrict__ W0, const unsigned short* __restrict__ W1,
    const unsigned short* __restrict__ W2,
    const float* __restrict__ b0, const float* __restrict__ b1, const float* __restrict__ b2,
    unsigned short* __restrict__ Cb, float* __restrict__ Cf) {
  __shared__ short lA[128 * 32];
  __shared__ short lB[128 * 32];
  const int K = 2048;
  int tid = threadIdx.x;
  int wave = tid >> 6, lane = tid & 63;
  int l15 = lane & 15, lg = lane >> 4;
  int tn = blockIdx.x, tm = blockIdx.y;
  const unsigned short* W; const float* bias = nullptr; int col0;
  if constexpr (MODE == 0) {
    if (tn < 16)      { W = W0; bias = b0; col0 = tn * 128; }
    else if (tn < 20) { W = W1; bias = b1; col0 = (tn - 16) * 128; }
    else              { W = W2; bias = b2; col0 = (tn - 20) * 128; }
  } else { W = W0; col0 = tn * 128; }
  int m0 = tm * 128;
  int wm = wave >> 1, wn = wave & 1;

  const unsigned short* gA0 = A + (size_t)(m0 + (tid >> 2)) * K + (tid & 3) * 8;
  const unsigned short* gA1 = gA0 + (size_t)64 * K;
  const unsigned short* gB0 = W + (size_t)(col0 + (tid >> 2)) * K + (tid & 3) * 8;
  const unsigned short* gB1 = gB0 + (size_t)64 * K;
  short* sA0 = &lA[wave * 512];
  short* sA1 = &lA[2048 + wave * 512];
  short* sB0 = &lB[wave * 512];
  short* sB1 = &lB[2048 + wave * 512];

  f32x4 acc[4][4];
#pragma unroll
  for (int m = 0; m < 4; ++m)
#pragma unroll
    for (int n = 0; n < 4; ++n) acc[m][n] = (f32x4){0.f, 0.f, 0.f, 0.f};

  for (int kt = 0; kt < K; kt += 32) {
    __syncthreads();
    gl_lds16(gA0 + kt, sA0);
    gl_lds16(gA1 + kt, sA1);
    gl_lds16(gB0 + kt, sB0);
    gl_lds16(gB1 + kt, sB1);
    asm volatile("s_waitcnt vmcnt(0)" ::: "memory");
    __syncthreads();
    s16x8 af[4], bfr[4];
    const short* pa = &lA[(wm * 64 + l15) * 32 + lg * 8];
    const short* pb = &lB[(wn * 64 + l15) * 32 + lg * 8];
#pragma unroll
    for (int m = 0; m < 4; ++m) af[m] = *(const s16x8*)(pa + m * 512);
#pragma unroll
    for (int n = 0; n < 4; ++n) bfr[n] = *(const s16x8*)(pb + n * 512);
#pragma unroll
    for (int m = 0; m < 4; ++m)
#pragma unroll
      for (int n = 0; n < 4; ++n)
        acc[m][n] = __builtin_amdgcn_mfma_f32_16x16x32_bf16(af[m], bfr[n], acc[m][n], 0, 0, 0);
  }

#pragma unroll
  for (int n = 0; n < 4; ++n) {
    int lcol = col0 + wn * 64 + n * 16 + l15;
    int gcol = tn * 128 + wn * 64 + n * 16 + l15;
    float bv = 0.f;
    if constexpr (MODE == 0) bv = bias[lcol];
#pragma unroll
    for (int m = 0; m < 4; ++m) {
      int row = m0 + wm * 64 + m * 16 + lg * 4;
#pragma unroll
      for (int r = 0; r < 4; ++r) {
        float v = acc[m][n][r] + bv;
        if constexpr (MODE == 0)
          Cb[(size_t)(row + r) * QKV_N + gcol] = f2bf(v);
        else
          Cf[(size_t)(row + r) * HID + gcol] = v;
      }
    }
  }
}

// ---------- 4) RoPE in-place ----------
__global__ void k_rope_apply(unsigned short* __restrict__ qkv,
                             const float* __restrict__ cost, const float* __restrict__ sint) {
  int t = blockIdx.x * blockDim.x + threadIdx.x;
  int chunk = t & 3;
  int head = (t >> 2) % 40;
  int row = t / 160;
  int colb = head < 32 ? head * 64 : 2048 + (head - 32) * 64;
  int d0 = chunk * 8;
  int s = row & (S_LEN - 1);
  unsigned short* p = qkv + (size_t)row * QKV_N + colb;
  s16x8 lo = *(s16x8*)(p + d0);
  s16x8 hi = *(s16x8*)(p + 32 + d0);
  const float* cb = cost + s * 32 + d0;
  const float* sb = sint + s * 32 + d0;
  f32x4 c0 = *(const f32x4*)cb, c1 = *(const f32x4*)(cb + 4);
  f32x4 s0 = *(const f32x4*)sb, s1 = *(const f32x4*)(sb + 4);
  float cc[8] = {c0[0], c0[1], c0[2], c0[3], c1[0], c1[1], c1[2], c1[3]};
  float ss[8] = {s0[0], s0[1], s0[2], s0[3], s1[0], s1[1], s1[2], s1[3]};
  s16x8 nlo, nhi;
#pragma unroll
  for (int j = 0; j < 8; ++j) {
    float xl = bf2f((unsigned short)lo[j]);
    float xh = bf2f((unsigned short)hi[j]);
    nlo[j] = (short)f2bf(xl * cc[j] - xh * ss[j]);
    nhi[j] = (short)f2bf(xh * cc[j] + xl * ss[j]);
  }
  *(s16x8*)(p + d0) = nlo;
  *(s16x8*)(p + 32 + d0) = nhi;
}

// ---------- 5) V transpose ----------
__global__ void k_vtrans(const unsigned short* __restrict__ qkv, unsigned short* __restrict__ vt) {
  __shared__ unsigned short t[64][80];
  int ts = blockIdx.x & 63, td = blockIdx.x >> 6;
  int tid = threadIdx.x;
#pragma unroll
  for (int L = 0; L < 2; ++L) {
    int c = L * 256 + tid;
    int row = c >> 3, ch = c & 7;
    const unsigned short* src = qkv + (size_t)(ts * 64 + row) * QKV_N + 2560 + td * 64 + ch * 8;
    s16x8 v = *(const s16x8*)src;
    int cs = (ch * 8) ^ ((row >> 3) << 3);
    *(s16x8*)&t[row][cs] = v;
  }
  __syncthreads();
  int b = (ts * 64) >> 11;
  int s0 = (ts * 64) & (S_LEN - 1);
#pragma unroll
  for (int L = 0; L < 2; ++L) {
    int c = L * 256 + tid;
    int d = c >> 3, sc = c & 7;
    s16x8 o;
#pragma unroll
    for (int j = 0; j < 8; ++j) o[j] = (short)t[sc * 8 + j][d ^ (sc << 3)];
    unsigned short* dst = vt + ((size_t)((b * 8 + td) * 64 + d)) * 2048 + s0 + sc * 8;
    *(s16x8*)dst = o;
  }
}

// ---------- 6) GQA causal flash attention: LDS-staged K/V, 8-wave paired blocks ----------
// block = 4 heads of one KV group x {tile 63-ip (waves 0-3), tile ip (waves 4-7)}.
// K and V^T tiles (64x64 bf16, XOR-swizzled via pre-swizzled gl_lds source) are staged
// cooperatively, double-buffered; stage(kb+1) issued before compute(kb).
__global__ __launch_bounds__(512, 4) void k_attn(const unsigned short* __restrict__ qkv,
                                                 const unsigned short* __restrict__ vt,
                                                 unsigned short* __restrict__ aout) {
  __shared__ unsigned short lK[2][4096];
  __shared__ unsigned short lV[2][4096];
  __shared__ unsigned short pl[8][2048];   // per-wave P tile [32][64], XOR-swizzled
  int wave = threadIdx.x >> 6, lane = threadIdx.x & 63;
  int l15 = lane & 15, lg = lane >> 4;
  int bi = blockIdx.x;            // 0..511, ip ascending = longest-first
  int ip = bi >> 4;               // 0..31
  int b  = (bi >> 3) & 1;
  int hg = bi & 7;
  int wgrp = wave >> 2;           // 0 = long tile, 1 = short tile
  int wh = wave & 3;
  int h = hg * 4 + wh;
  int t = wgrp ? ip : (63 - ip);
  int q0 = t * 32;
  int kbend = t >> 1;             // this wave-group's last kb
  int kbmaxB = (63 - ip) >> 1;    // block loop bound

  const unsigned short* qb_ = qkv + (size_t)(b * S_LEN) * QKV_N + h * 64;
  const unsigned short* kbase = qkv + (size_t)(b * S_LEN) * QKV_N + 2048 + hg * 64;
  const unsigned short* vbase = vt + (size_t)((b * NKVH + hg) * 64) * 2048;
  unsigned short* pw = &pl[wave][0];
  int sw = (l15 & 7) << 3;        // element-XOR swizzle for this lane's rows

  // staging lane geometry: lane L -> row wave*8 + (L>>3), 16B slot (L&7), swizzled source
  int srow = wave * 8 + (lane >> 3);
  int ssw = 8 * ((lane & 7) ^ ((lane >> 3) & 7));
  const unsigned short* gk0 = kbase + (size_t)srow * QKV_N + ssw;
  const unsigned short* gv0 = vbase + (size_t)srow * 2048 + ssw;
  short* lkd0 = (short*)&lK[0][wave * 512]; short* lkd1 = (short*)&lK[1][wave * 512];
  short* lvd0 = (short*)&lV[0][wave * 512]; short* lvd1 = (short*)&lV[1][wave * 512];

  // Q fragments (B-operand of swapped QK^T)
  s16x8 aq[2][2];
#pragma unroll
  for (int m = 0; m < 2; ++m)
#pragma unroll
    for (int ks = 0; ks < 2; ++ks)
      aq[m][ks] = *(const s16x8*)(qb_ + (size_t)(q0 + m * 16 + l15) * QKV_N + ks * 32 + lg * 8);

  f32x4 acc[2][4];
  float mrow[2], lrow[2];
#pragma unroll
  for (int m = 0; m < 2; ++m) {
#pragma unroll
    for (int dt = 0; dt < 4; ++dt) acc[m][dt] = (f32x4){0.f, 0.f, 0.f, 0.f};
    mrow[m] = -3.0e38f; lrow[m] = 0.f;
  }

  // prologue: stage kb=0 into buffer 0
  gl_lds16(gk0, lkd0);
  gl_lds16(gv0, lvd0);
  asm volatile("s_waitcnt vmcnt(0)" ::: "memory");
  __syncthreads();

  for (int kb = 0; kb <= kbmaxB; ++kb) {
    const unsigned short* lk = &lK[kb & 1][0];
    const unsigned short* lv = &lV[kb & 1][0];
    // issue next-tile staging first (latency hides under compute)
    if (kb < kbmaxB) {
      size_t go = (size_t)(kb + 1) * 64;
      if ((kb & 1) == 0) { gl_lds16(gk0 + go * QKV_N, lkd1); gl_lds16(gv0 + go, lvd1); }
      else               { gl_lds16(gk0 + go * QKV_N, lkd0); gl_lds16(gv0 + go, lvd0); }
    }
    if (kb <= kbend) {
      bool need_mask = (kb == kbend);
#pragma unroll
      for (int m = 0; m < 2; ++m) {
        f32x4 z[4];
        __builtin_amdgcn_s_setprio(1);
#pragma unroll
        for (int nt = 0; nt < 4; ++nt) {
          s16x8 k0 = *(const s16x8*)(lk + (nt * 16 + l15) * 64 + ((lg * 8) ^ sw));
          s16x8 k1 = *(const s16x8*)(lk + (nt * 16 + l15) * 64 + ((32 + lg * 8) ^ sw));
          f32x4 zz = (f32x4){0.f, 0.f, 0.f, 0.f};
          zz = __builtin_amdgcn_mfma_f32_16x16x32_bf16(k0, aq[m][0], zz, 0, 0, 0);
          zz = __builtin_amdgcn_mfma_f32_16x16x32_bf16(k1, aq[m][1], zz, 0, 0, 0);
          z[nt] = zz;
        }
        __builtin_amdgcn_s_setprio(0);
        float s[16];
        int q = q0 + m * 16 + l15;
#pragma unroll
        for (int nt = 0; nt < 4; ++nt)
#pragma unroll
          for (int r = 0; r < 4; ++r) {
            float v = z[nt][r] * 0.125f;
            if (need_mask) {
              int k = kb * 64 + nt * 16 + lg * 4 + r;
              if (k > q) v = -3.0e38f;
            }
            s[nt * 4 + r] = v;
          }
        float mx = s[0];
#pragma unroll
        for (int i = 1; i < 16; ++i) mx = fmaxf(mx, s[i]);
        mx = fmaxf(mx, __shfl_xor(mx, 16));
        mx = fmaxf(mx, __shfl_xor(mx, 32));
        float nm = fmaxf(mrow[m], mx);
        float corr = __expf(mrow[m] - nm);
        mrow[m] = nm;
        float rs = 0.f;
#pragma unroll
        for (int nt = 0; nt < 4; ++nt) {
          s16x4 pk;
#pragma unroll
          for (int r = 0; r < 4; ++r) {
            float p = __expf(s[nt * 4 + r] - nm);
            rs += p;
            pk[r] = (short)f2bf(p);
          }
          *(s16x4*)(pw + (m * 16 + l15) * 64 + ((nt * 16 + lg * 4) ^ sw)) = pk;
        }
        rs += __shfl_xor(rs, 16);
        rs += __shfl_xor(rs, 32);
        lrow[m] = lrow[m] * corr + rs;
#pragma unroll
        for (int r = 0; r < 4; ++r) {
          float cr = __shfl(corr, lg * 4 + r);
#pragma unroll
          for (int dt = 0; dt < 4; ++dt) acc[m][dt][r] *= cr;
        }
      }
      // PV
      s16x8 pa[2][2];
#pragma unroll
      for (int m = 0; m < 2; ++m)
#pragma unroll
        for (int ks = 0; ks < 2; ++ks)
          pa[m][ks] = *(const s16x8*)(pw + (m * 16 + l15) * 64 + ((ks * 32 + lg * 8) ^ sw));
      __builtin_amdgcn_s_setprio(1);
#pragma unroll
      for (int dt = 0; dt < 4; ++dt) {
        s16x8 v0 = *(const s16x8*)(lv + (dt * 16 + l15) * 64 + ((lg * 8) ^ sw));
        s16x8 v1 = *(const s16x8*)(lv + (dt * 16 + l15) * 64 + ((32 + lg * 8) ^ sw));
#pragma unroll
        for (int m = 0; m < 2; ++m) {
          acc[m][dt] = __builtin_amdgcn_mfma_f32_16x16x32_bf16(pa[m][0], v0, acc[m][dt], 0, 0, 0);
          acc[m][dt] = __builtin_amdgcn_mfma_f32_16x16x32_bf16(pa[m][1], v1, acc[m][dt], 0, 0, 0);
        }
      }
      __builtin_amdgcn_s_setprio(0);
    }
    asm volatile("s_waitcnt vmcnt(0)" ::: "memory");
    __syncthreads();
  }

  // epilogue: O = acc / l  (acc rows q = lg*4+r; lrow lives at lane l15=q -> shfl)
  unsigned short* ob = aout + (size_t)(b * S_LEN) * HID + h * 64;
#pragma unroll
  for (int m = 0; m < 2; ++m)
#pragma unroll
    for (int r = 0; r < 4; ++r) {
      float lr = __shfl(lrow[m], lg * 4 + r);
      float inv = 1.0f / lr;
#pragma unroll
      for (int dt = 0; dt < 4; ++dt)
        ob[(size_t)(q0 + m * 16 + lg * 4 + r) * HID + dt * 16 + l15] = f2bf(acc[m][dt][r] * inv);
    }
}

// ---------- launch ----------
extern "C" void kernel_launch(void* const* d_in, const int* in_sizes, int n_in,
                              void* d_out, int out_size, void* d_ws, size_t ws_size,
                              hipStream_t stream) {
  const float* x  = (const float*)d_in[0];
  const float* qw = (const float*)d_in[1];
  const float* qb = (const float*)d_in[2];
  const float* kw = (const float*)d_in[3];
  const float* kbias = (const float*)d_in[4];
  const float* vw = (const float*)d_in[5];
  const float* vbias = (const float*)d_in[6];
  const float* ow = (const float*)d_in[7];

  unsigned short* Xb  = (unsigned short*)d_ws;          // 8388608
  unsigned short* Wqb = Xb + 8388608;                   // 4194304
  unsigned short* Wkb = Wqb + 4194304;                  // 1048576
  unsigned short* Wvb = Wkb + 1048576;                  // 1048576
  unsigned short* Wob = Wvb + 1048576;                  // 4194304
  unsigned short* QKV = Wob + 4194304;                  // 4096*3072
  unsigned short* VT  = QKV + 12582912;                 // 2*8*64*2048
  unsigned short* AO  = VT + 2097152;                   // 4096*2048
  float* COS = (float*)(AO + 8388608);                  // 65536 f32
  float* SIN = COS + 65536;

  k_convert<<<1024, 256, 0, stream>>>(x, qw, kw, vw, ow, Xb);
  k_rope_table<<<256, 256, 0, stream>>>(COS, SIN);
  k_gemm<0><<<dim3(24, 32), 256, 0, stream>>>(Xb, Wqb, Wkb, Wvb, qb, kbias, vbias, QKV, nullptr);
  k_rope_apply<<<2560, 256, 0, stream>>>(QKV, COS, SIN);
  k_vtrans<<<512, 256, 0, stream>>>(QKV, VT);
  k_attn<<<512, 512, 0, stream>>>(QKV, VT, AO);
  k_gemm<1><<<dim3(16, 32), 256, 0, stream>>>(AO, Wob, nullptr, nullptr,
                                              nullptr, nullptr, nullptr, nullptr, (float*)d_out);
}

// Round 6
// 208.581 us; speedup vs baseline: 1.5449x; 1.0907x over previous
//
#include <hip/hip_runtime.h>
#include <stdint.h>
#include <stddef.h>

// ---------- types ----------
typedef __attribute__((ext_vector_type(8))) short s16x8;
typedef __attribute__((ext_vector_type(4))) short s16x4;
typedef __attribute__((ext_vector_type(4))) float f32x4;
typedef __attribute__((ext_vector_type(2))) unsigned int u32x2;

#define S_LEN 2048
#define HID 2048
#define QKV_N 3072
#define NHEAD 32
#define NKVH 8

__device__ __forceinline__ unsigned short f2bf(float f) {
  union { float f; unsigned u; } a; a.f = f;
  unsigned u = a.u;
  u += 0x7fffu + ((u >> 16) & 1u);
  return (unsigned short)(u >> 16);
}
__device__ __forceinline__ float bf2f(unsigned short h) {
  union { unsigned u; float f; } a; a.u = ((unsigned)h) << 16;
  return a.f;
}
__device__ __forceinline__ unsigned cvt_pk_bf16(float a, float b) {
  unsigned r;
  asm("v_cvt_pk_bf16_f32 %0, %1, %2" : "=v"(r) : "v"(a), "v"(b));
  return r;  // low16 = bf16(a), high16 = bf16(b)
}
__device__ __forceinline__ void gl_lds16(const unsigned short* g, short* l) {
  __builtin_amdgcn_global_load_lds(
      (const __attribute__((address_space(1))) unsigned int*)g,
      (__attribute__((address_space(3))) unsigned int*)l, 16, 0, 0);
}

// ---------- 1) fp32 -> bf16 convert ----------
__global__ void k_convert(const float* __restrict__ x, const float* __restrict__ wq,
                          const float* __restrict__ wk, const float* __restrict__ wv,
                          const float* __restrict__ wo, unsigned short* __restrict__ dst) {
  const unsigned n4 = 18874368u / 4u;
  for (unsigned i = blockIdx.x * blockDim.x + threadIdx.x; i < n4;
       i += gridDim.x * blockDim.x) {
    unsigned e = i * 4u;
    const float* src; unsigned off;
    if (e < 8388608u)       { src = x;  off = e; }
    else if (e < 12582912u) { src = wq; off = e - 8388608u; }
    else if (e < 13631488u) { src = wk; off = e - 12582912u; }
    else if (e < 14680064u) { src = wv; off = e - 13631488u; }
    else                    { src = wo; off = e - 14680064u; }
    f32x4 v = *(const f32x4*)(src + off);
    s16x4 o;
    o[0] = (short)f2bf(v[0]); o[1] = (short)f2bf(v[1]);
    o[2] = (short)f2bf(v[2]); o[3] = (short)f2bf(v[3]);
    *(s16x4*)(dst + e) = o;
  }
}

// ---------- 2) RoPE cos/sin table [2048][32] ----------
__global__ void k_rope_table(float* __restrict__ cost, float* __restrict__ sint) {
  int idx = blockIdx.x * 256 + threadIdx.x;
  int i = idx & 31, s = idx >> 5;
  float inv = powf(10000.0f, -(float)(2 * i) / 64.0f);
  float ang = (float)s * inv;
  cost[idx] = cosf(ang);
  sint[idx] = sinf(ang);
}

// ---------- 3/7) GEMM: C[M,*] = A[M,2048] * W[*,2048]^T (+bias, +RoPE for MODE 0) ----------
template <int MODE>
__global__ __launch_bounds__(256) void k_gemm(
    const unsigned short* __restrict__ A,
    const unsigned short* __restrict__ W0, const unsigned short* __restrict__ W1,
    const unsigned short* __restrict__ W2,
    const float* __restrict__ b0, const float* __restrict__ b1, const float* __restrict__ b2,
    const float* __restrict__ ct, const float* __restrict__ st,
    unsigned short* __restrict__ Cb, float* __restrict__ Cf) {
  __shared__ short lA[128 * 32];
  __shared__ short lB[128 * 32];
  const int K = 2048;
  int tid = threadIdx.x;
  int wave = tid >> 6, lane = tid & 63;
  int l15 = lane & 15, lg = lane >> 4;
  int tn = blockIdx.x, tm = blockIdx.y;
  const unsigned short* W; const float* bias = nullptr; int col0;
  if constexpr (MODE == 0) {
    if (tn < 16)      { W = W0; bias = b0; col0 = tn * 128; }
    else if (tn < 20) { W = W1; bias = b1; col0 = (tn - 16) * 128; }
    else              { W = W2; bias = b2; col0 = (tn - 20) * 128; }
  } else { W = W0; col0 = tn * 128; }
  int m0 = tm * 128;
  int wm = wave >> 1, wn = wave & 1;

  const unsigned short* gA0 = A + (size_t)(m0 + (tid >> 2)) * K + (tid & 3) * 8;
  const unsigned short* gA1 = gA0 + (size_t)64 * K;
  const unsigned short* gB0 = W + (size_t)(col0 + (tid >> 2)) * K + (tid & 3) * 8;
  const unsigned short* gB1 = gB0 + (size_t)64 * K;
  short* sA0 = &lA[wave * 512];
  short* sA1 = &lA[2048 + wave * 512];
  short* sB0 = &lB[wave * 512];
  short* sB1 = &lB[2048 + wave * 512];

  f32x4 acc[4][4];
#pragma unroll
  for (int m = 0; m < 4; ++m)
#pragma unroll
    for (int n = 0; n < 4; ++n) acc[m][n] = (f32x4){0.f, 0.f, 0.f, 0.f};

  for (int kt = 0; kt < K; kt += 32) {
    __syncthreads();
    gl_lds16(gA0 + kt, sA0);
    gl_lds16(gA1 + kt, sA1);
    gl_lds16(gB0 + kt, sB0);
    gl_lds16(gB1 + kt, sB1);
    asm volatile("s_waitcnt vmcnt(0)" ::: "memory");
    __syncthreads();
    s16x8 af[4], bfr[4];
    const short* pa = &lA[(wm * 64 + l15) * 32 + lg * 8];
    const short* pb = &lB[(wn * 64 + l15) * 32 + lg * 8];
#pragma unroll
    for (int m = 0; m < 4; ++m) af[m] = *(const s16x8*)(pa + m * 512);
#pragma unroll
    for (int n = 0; n < 4; ++n) bfr[n] = *(const s16x8*)(pb + n * 512);
#pragma unroll
    for (int m = 0; m < 4; ++m)
#pragma unroll
      for (int n = 0; n < 4; ++n)
        acc[m][n] = __builtin_amdgcn_mfma_f32_16x16x32_bf16(af[m], bfr[n], acc[m][n], 0, 0, 0);
  }

  if constexpr (MODE == 0) {
    // epilogue with fused bias + RoPE. Wave's 64-col slice = one head; pair (d, d+32)
    // = (acc[.][n], acc[.][n+2]); cos/sin idx = d&31 (same for both halves).
    bool rope = (tn < 20);  // Q and K heads; V (tn>=20) passes through
#pragma unroll
    for (int n = 0; n < 2; ++n) {
      int lcol = col0 + wn * 64 + n * 16 + l15;
      int gcol = tn * 128 + wn * 64 + n * 16 + l15;
      float blo = bias[lcol], bhi = bias[lcol + 32];
      int i = n * 16 + l15;
#pragma unroll
      for (int m = 0; m < 4; ++m) {
        int row = m0 + wm * 64 + m * 16 + lg * 4;
#pragma unroll
        for (int r = 0; r < 4; ++r) {
          float xl = acc[m][n][r] + blo;
          float xh = acc[m][n + 2][r] + bhi;
          if (rope) {
            int s = (row + r) & (S_LEN - 1);
            float c = ct[s * 32 + i], sn = st[s * 32 + i];
            float nl = xl * c - xh * sn;
            xh = xh * c + xl * sn;
            xl = nl;
          }
          Cb[(size_t)(row + r) * QKV_N + gcol] = f2bf(xl);
          Cb[(size_t)(row + r) * QKV_N + gcol + 32] = f2bf(xh);
        }
      }
    }
  } else {
#pragma unroll
    for (int n = 0; n < 4; ++n) {
      int gcol = tn * 128 + wn * 64 + n * 16 + l15;
#pragma unroll
      for (int m = 0; m < 4; ++m) {
        int row = m0 + wm * 64 + m * 16 + lg * 4;
#pragma unroll
        for (int r = 0; r < 4; ++r)
          Cf[(size_t)(row + r) * HID + gcol] = acc[m][n][r];
      }
    }
  }
}

// ---------- 5) V transpose ----------
__global__ void k_vtrans(const unsigned short* __restrict__ qkv, unsigned short* __restrict__ vt) {
  __shared__ unsigned short t[64][80];
  int ts = blockIdx.x & 63, td = blockIdx.x >> 6;
  int tid = threadIdx.x;
#pragma unroll
  for (int L = 0; L < 2; ++L) {
    int c = L * 256 + tid;
    int row = c >> 3, ch = c & 7;
    const unsigned short* src = qkv + (size_t)(ts * 64 + row) * QKV_N + 2560 + td * 64 + ch * 8;
    s16x8 v = *(const s16x8*)src;
    int cs = (ch * 8) ^ ((row >> 3) << 3);
    *(s16x8*)&t[row][cs] = v;
  }
  __syncthreads();
  int b = (ts * 64) >> 11;
  int s0 = (ts * 64) & (S_LEN - 1);
#pragma unroll
  for (int L = 0; L < 2; ++L) {
    int c = L * 256 + tid;
    int d = c >> 3, sc = c & 7;
    s16x8 o;
#pragma unroll
    for (int j = 0; j < 8; ++j) o[j] = (short)t[sc * 8 + j][d ^ (sc << 3)];
    unsigned short* dst = vt + ((size_t)((b * 8 + td) * 64 + d)) * 2048 + s0 + sc * 8;
    *(s16x8*)dst = o;
  }
}

// ---------- 6) GQA causal flash attention: LDS-staged K/V, 8-wave paired blocks ----------
// Softmax in exp2 domain (scale folded), defer-max THR=8, cvt_pk P-pack.
__global__ __launch_bounds__(512, 4) void k_attn(const unsigned short* __restrict__ qkv,
                                                 const unsigned short* __restrict__ vt,
                                                 unsigned short* __restrict__ aout) {
  __shared__ unsigned short lK[2][4096];
  __shared__ unsigned short lV[2][4096];
  __shared__ unsigned short pl[8][2048];   // per-wave P tile [32][64], XOR-swizzled
  int wave = threadIdx.x >> 6, lane = threadIdx.x & 63;
  int l15 = lane & 15, lg = lane >> 4;
  int bi = blockIdx.x;            // 0..511, ip ascending = longest-first
  int ip = bi >> 4;               // 0..31
  int b  = (bi >> 3) & 1;
  int hg = bi & 7;
  int wgrp = wave >> 2;           // 0 = long tile, 1 = short tile
  int wh = wave & 3;
  int h = hg * 4 + wh;
  int t = wgrp ? ip : (63 - ip);
  int q0 = t * 32;
  int kbend = t >> 1;             // this wave-group's last kb
  int kbmaxB = (63 - ip) >> 1;    // block loop bound

  const unsigned short* qb_ = qkv + (size_t)(b * S_LEN) * QKV_N + h * 64;
  const unsigned short* kbase = qkv + (size_t)(b * S_LEN) * QKV_N + 2048 + hg * 64;
  const unsigned short* vbase = vt + (size_t)((b * NKVH + hg) * 64) * 2048;
  unsigned short* pw = &pl[wave][0];
  int sw = (l15 & 7) << 3;        // element-XOR swizzle for this lane's rows

  int srow = wave * 8 + (lane >> 3);
  int ssw = 8 * ((lane & 7) ^ ((lane >> 3) & 7));
  const unsigned short* gk0 = kbase + (size_t)srow * QKV_N + ssw;
  const unsigned short* gv0 = vbase + (size_t)srow * 2048 + ssw;
  short* lkd0 = (short*)&lK[0][wave * 512]; short* lkd1 = (short*)&lK[1][wave * 512];
  short* lvd0 = (short*)&lV[0][wave * 512]; short* lvd1 = (short*)&lV[1][wave * 512];

  // Q fragments (B-operand of swapped QK^T)
  s16x8 aq[2][2];
#pragma unroll
  for (int m = 0; m < 2; ++m)
#pragma unroll
    for (int ks = 0; ks < 2; ++ks)
      aq[m][ks] = *(const s16x8*)(qb_ + (size_t)(q0 + m * 16 + l15) * QKV_N + ks * 32 + lg * 8);

  f32x4 acc[2][4];
  float mrow[2], lrow[2];
#pragma unroll
  for (int m = 0; m < 2; ++m) {
#pragma unroll
    for (int dt = 0; dt < 4; ++dt) acc[m][dt] = (f32x4){0.f, 0.f, 0.f, 0.f};
    mrow[m] = -3.0e38f; lrow[m] = 0.f;
  }

  const float CSC = 0.125f * 1.44269504f;  // scale * log2(e)

  gl_lds16(gk0, lkd0);
  gl_lds16(gv0, lvd0);
  asm volatile("s_waitcnt vmcnt(0)" ::: "memory");
  __syncthreads();

  for (int kb = 0; kb <= kbmaxB; ++kb) {
    const unsigned short* lk = &lK[kb & 1][0];
    const unsigned short* lv = &lV[kb & 1][0];
    if (kb < kbmaxB) {
      size_t go = (size_t)(kb + 1) * 64;
      if ((kb & 1) == 0) { gl_lds16(gk0 + go * QKV_N, lkd1); gl_lds16(gv0 + go, lvd1); }
      else               { gl_lds16(gk0 + go * QKV_N, lkd0); gl_lds16(gv0 + go, lvd0); }
    }
    if (kb <= kbend) {
      bool need_mask = (kb == kbend);
#pragma unroll
      for (int m = 0; m < 2; ++m) {
        f32x4 z[4];
        __builtin_amdgcn_s_setprio(1);
#pragma unroll
        for (int nt = 0; nt < 4; ++nt) {
          s16x8 k0 = *(const s16x8*)(lk + (nt * 16 + l15) * 64 + ((lg * 8) ^ sw));
          s16x8 k1 = *(const s16x8*)(lk + (nt * 16 + l15) * 64 + ((32 + lg * 8) ^ sw));
          f32x4 zz = (f32x4){0.f, 0.f, 0.f, 0.f};
          zz = __builtin_amdgcn_mfma_f32_16x16x32_bf16(k0, aq[m][0], zz, 0, 0, 0);
          zz = __builtin_amdgcn_mfma_f32_16x16x32_bf16(k1, aq[m][1], zz, 0, 0, 0);
          z[nt] = zz;
        }
        __builtin_amdgcn_s_setprio(0);
        float s[16];
        int q = q0 + m * 16 + l15;
#pragma unroll
        for (int nt = 0; nt < 4; ++nt)
#pragma unroll
          for (int r = 0; r < 4; ++r) {
            float v = z[nt][r] * CSC;
            if (need_mask) {
              int k = kb * 64 + nt * 16 + lg * 4 + r;
              if (k > q) v = -1.0e30f;
            }
            s[nt * 4 + r] = v;
          }
        // row max (tree) + cross-lg reduce
        float m01 = fmaxf(s[0], s[1]), m23 = fmaxf(s[2], s[3]);
        float m45 = fmaxf(s[4], s[5]), m67 = fmaxf(s[6], s[7]);
        float m89 = fmaxf(s[8], s[9]), mab = fmaxf(s[10], s[11]);
        float mcd = fmaxf(s[12], s[13]), mef = fmaxf(s[14], s[15]);
        float mx = fmaxf(fmaxf(fmaxf(m01, m23), fmaxf(m45, m67)),
                         fmaxf(fmaxf(m89, mab), fmaxf(mcd, mef)));
        mx = fmaxf(mx, __shfl_xor(mx, 16));
        mx = fmaxf(mx, __shfl_xor(mx, 32));
        // defer-max: only rescale when some row grew past THR=8 (log2 units)
        if (!__all(mx <= mrow[m] + 8.0f)) {
          float nm = fmaxf(mrow[m], mx);
          float corr = __builtin_amdgcn_exp2f(mrow[m] - nm);
          mrow[m] = nm;
          lrow[m] *= corr;
#pragma unroll
          for (int r = 0; r < 4; ++r) {
            float cr = __shfl(corr, lg * 4 + r);
#pragma unroll
            for (int dt = 0; dt < 4; ++dt) acc[m][dt][r] *= cr;
          }
        }
        float nm = mrow[m];
        float rs = 0.f;
#pragma unroll
        for (int nt = 0; nt < 4; ++nt) {
          float p0 = __builtin_amdgcn_exp2f(s[nt * 4 + 0] - nm);
          float p1 = __builtin_amdgcn_exp2f(s[nt * 4 + 1] - nm);
          float p2 = __builtin_amdgcn_exp2f(s[nt * 4 + 2] - nm);
          float p3 = __builtin_amdgcn_exp2f(s[nt * 4 + 3] - nm);
          rs += (p0 + p1) + (p2 + p3);
          u32x2 w;
          w[0] = cvt_pk_bf16(p0, p1);
          w[1] = cvt_pk_bf16(p2, p3);
          *(u32x2*)(pw + (m * 16 + l15) * 64 + ((nt * 16 + lg * 4) ^ sw)) = w;
        }
        rs += __shfl_xor(rs, 16);
        rs += __shfl_xor(rs, 32);
        lrow[m] += rs;
      }
      // PV
      s16x8 pa[2][2];
#pragma unroll
      for (int m = 0; m < 2; ++m)
#pragma unroll
        for (int ks = 0; ks < 2; ++ks)
          pa[m][ks] = *(const s16x8*)(pw + (m * 16 + l15) * 64 + ((ks * 32 + lg * 8) ^ sw));
      __builtin_amdgcn_s_setprio(1);
#pragma unroll
      for (int dt = 0; dt < 4; ++dt) {
        s16x8 v0 = *(const s16x8*)(lv + (dt * 16 + l15) * 64 + ((lg * 8) ^ sw));
        s16x8 v1 = *(const s16x8*)(lv + (dt * 16 + l15) * 64 + ((32 + lg * 8) ^ sw));
#pragma unroll
        for (int m = 0; m < 2; ++m) {
          acc[m][dt] = __builtin_amdgcn_mfma_f32_16x16x32_bf16(pa[m][0], v0, acc[m][dt], 0, 0, 0);
          acc[m][dt] = __builtin_amdgcn_mfma_f32_16x16x32_bf16(pa[m][1], v1, acc[m][dt], 0, 0, 0);
        }
      }
      __builtin_amdgcn_s_setprio(0);
    }
    asm volatile("s_waitcnt vmcnt(0)" ::: "memory");
    __syncthreads();
  }

  // epilogue: O = acc / l  (acc rows q = lg*4+r; lrow lives at lane l15=q -> shfl)
  unsigned short* ob = aout + (size_t)(b * S_LEN) * HID + h * 64;
#pragma unroll
  for (int m = 0; m < 2; ++m)
#pragma unroll
    for (int r = 0; r < 4; ++r) {
      float lr = __shfl(lrow[m], lg * 4 + r);
      float inv = 1.0f / lr;
#pragma unroll
      for (int dt = 0; dt < 4; ++dt)
        ob[(size_t)(q0 + m * 16 + lg * 4 + r) * HID + dt * 16 + l15] = f2bf(acc[m][dt][r] * inv);
    }
}

// ---------- launch ----------
extern "C" void kernel_launch(void* const* d_in, const int* in_sizes, int n_in,
                              void* d_out, int out_size, void* d_ws, size_t ws_size,
                              hipStream_t stream) {
  const float* x  = (const float*)d_in[0];
  const float* qw = (const float*)d_in[1];
  const float* qb = (const float*)d_in[2];
  const float* kw = (const float*)d_in[3];
  const float* kbias = (const float*)d_in[4];
  const float* vw = (const float*)d_in[5];
  const float* vbias = (const float*)d_in[6];
  const float* ow = (const float*)d_in[7];

  unsigned short* Xb  = (unsigned short*)d_ws;          // 8388608
  unsigned short* Wqb = Xb + 8388608;                   // 4194304
  unsigned short* Wkb = Wqb + 4194304;                  // 1048576
  unsigned short* Wvb = Wkb + 1048576;                  // 1048576
  unsigned short* Wob = Wvb + 1048576;                  // 4194304
  unsigned short* QKV = Wob + 4194304;                  // 4096*3072
  unsigned short* VT  = QKV + 12582912;                 // 2*8*64*2048
  unsigned short* AO  = VT + 2097152;                   // 4096*2048
  float* COS = (float*)(AO + 8388608);                  // 65536 f32
  float* SIN = COS + 65536;

  k_convert<<<1024, 256, 0, stream>>>(x, qw, kw, vw, ow, Xb);
  k_rope_table<<<256, 256, 0, stream>>>(COS, SIN);
  k_gemm<0><<<dim3(24, 32), 256, 0, stream>>>(Xb, Wqb, Wkb, Wvb, qb, kbias, vbias,
                                              COS, SIN, QKV, nullptr);
  k_vtrans<<<512, 256, 0, stream>>>(QKV, VT);
  k_attn<<<512, 512, 0, stream>>>(QKV, VT, AO);
  k_gemm<1><<<dim3(16, 32), 256, 0, stream>>>(AO, Wob, nullptr, nullptr,
                                              nullptr, nullptr, nullptr, nullptr, nullptr,
                                              nullptr, (float*)d_out);
}